// Round 4
// baseline (49.275 us; speedup 1.0000x reference)
//
#include <hip/hip_runtime.h>
#include <math.h>

#define HEADS 8
#define BUCKETS 64
#define DIM 64
#define SEQ 8192
#define BH 32
#define ROWS_PER_BUCKET (SEQ / BUCKETS)   // 128
#define EPS 1e-6f
#define LOG2E 1.4426950408889634f
#define INV_T (1.0f / 0.7f)
#define SINKHORN_ITER_COUNT 8

static __device__ __forceinline__ float fast_exp2(float x) {
#if __has_builtin(__builtin_amdgcn_exp2f)
    return __builtin_amdgcn_exp2f(x);     // v_exp_f32
#else
    return exp2f(x);
#endif
}
static __device__ __forceinline__ float fast_log2(float x) {
#if __has_builtin(__builtin_amdgcn_logf)
    return __builtin_amdgcn_logf(x);      // v_log_f32 (log2)
#else
    return log2f(x);
#endif
}

// ---------------------------------------------------------------------------
// Kernel 1: bucket means + positional embedding — ONE WAVE PER BUCKET.
// 4096 wave-tasks (2 inputs x 32 bh x 64 buckets); 1024 blocks x 256 thr.
// Thread l: chunk c = l&15 (dims 4c..4c+3), row-residue rs = l>>4.
// Load i (i=0..31): row 4i+rs, so each wave instruction reads rows
// [4i,4i+3] x 256B = 1KB CONTIGUOUS. Reduce over rs via 2 shfl_xor.
// No LDS, no __syncthreads -> loads stay in flight the whole kernel.
// ---------------------------------------------------------------------------
__global__ __launch_bounds__(256) void bucket_mean_kernel(
    const float* __restrict__ q, const float* __restrict__ k,
    const float* __restrict__ q_pos, const float* __restrict__ k_pos,
    float* __restrict__ sq, float* __restrict__ sk) {

    const int lane = threadIdx.x & 63;
    const int task = blockIdx.x * 4 + (threadIdx.x >> 6);   // 0..4095
    const int which = task >> 11;            // 0 = q, 1 = k
    const int bh = (task >> 6) & 31;
    const int bucket = task & 63;

    const float* __restrict__ src = which ? k : q;
    const float* __restrict__ pos = which ? k_pos : q_pos;
    float* __restrict__ dst = which ? sk : sq;

    const int c = lane & 15;
    const int rs = lane >> 4;

    const float4* __restrict__ s4 = (const float4*)(src
        + ((size_t)bh * SEQ + (size_t)bucket * ROWS_PER_BUCKET) * DIM);

    float4 acc = make_float4(0.f, 0.f, 0.f, 0.f);
#pragma unroll
    for (int i = 0; i < 32; ++i) {
        float4 v = s4[(size_t)(i * 4 + rs) * (DIM / 4) + c];
        acc.x += v.x; acc.y += v.y; acc.z += v.z; acc.w += v.w;
    }

    // butterfly over the 4 row-residues (lanes l, l^16, l^32, l^48)
#pragma unroll
    for (int off = 16; off <= 32; off <<= 1) {
        acc.x += __shfl_xor(acc.x, off);
        acc.y += __shfl_xor(acc.y, off);
        acc.z += __shfl_xor(acc.z, off);
        acc.w += __shfl_xor(acc.w, off);
    }

    const int head = bh & (HEADS - 1);
    float4 p = ((const float4*)pos)[(head * BUCKETS + bucket) * (DIM / 4) + c];
    const float inv = 1.0f / (float)ROWS_PER_BUCKET;
    float4 r;
    r.x = acc.x * inv + p.x; r.y = acc.y * inv + p.y;
    r.z = acc.z * inv + p.z; r.w = acc.w * inv + p.w;

    if (lane < 16)
        ((float4*)dst)[(bh * BUCKETS + bucket) * (DIM / 4) + c] = r;
}

// ---------------------------------------------------------------------------
// Kernel 2: per-bh R = sq@sk^T, gumbel-sinkhorn in BASE-2 log space.
// grid=BH, 1024 threads (16 waves). ~6 us.
// ---------------------------------------------------------------------------
__global__ __launch_bounds__(1024) void sinkhorn_kernel(
    const float* __restrict__ sq, const float* __restrict__ sk,
    const float* __restrict__ gumbel, float* __restrict__ out) {

    const int bh = blockIdx.x;
    const int t = threadIdx.x;
    const int lane = t & 63;
    const int w = t >> 6;     // wave 0..15

    __shared__ float sq_s[64][64];   // broadcast-read: no pad needed
    __shared__ float sk_s[64][65];
    __shared__ float r_s[64][65];

    // Stage sq, sk: 1024 float4 each, one per thread.
    {
        const float4* __restrict__ sq4 = (const float4*)(sq + bh * 4096);
        const float4* __restrict__ sk4 = (const float4*)(sk + bh * 4096);
        int row = t >> 4, ch = t & 15;
        float4 v = sq4[t];
        *(float4*)&sq_s[row][ch * 4] = v;
        float4 u = sk4[t];                   // padded row: scalar stores
        sk_s[row][ch * 4 + 0] = u.x; sk_s[row][ch * 4 + 1] = u.y;
        sk_s[row][ch * 4 + 2] = u.z; sk_s[row][ch * 4 + 3] = u.w;
    }
    __syncthreads();

    // R[i][j], wave w owns rows i = w*4+ii, lane = j.
    float acc[4];
#pragma unroll
    for (int ii = 0; ii < 4; ++ii) acc[ii] = 0.f;
    for (int d = 0; d < 64; ++d) {
        float skv = sk_s[lane][d];
#pragma unroll
        for (int ii = 0; ii < 4; ++ii)
            acc[ii] = fmaf(sq_s[w * 4 + ii][d], skv, acc[ii]);
    }

    // y = (log2(relu(R)+eps) + g*log2e) / T
    const float* __restrict__ g = gumbel + bh * 4096;
#pragma unroll
    for (int ii = 0; ii < 4; ++ii) {
        int i = w * 4 + ii;
        float Rp = fmaxf(acc[ii], 0.f) + EPS;
        float y = (fast_log2(Rp) + g[i * 64 + lane] * LOG2E) * INV_T;
        r_s[i][lane] = y;
    }
    __syncthreads();

    for (int it = 0; it < SINKHORN_ITER_COUNT; ++it) {
        // axis=2 (rows): y -= log2(sum_j 2^y)
#pragma unroll
        for (int ii = 0; ii < 4; ++ii) {
            int i = w * 4 + ii;
            float x = r_s[i][lane];
            float s = fast_exp2(x);
#pragma unroll
            for (int off = 32; off > 0; off >>= 1) s += __shfl_xor(s, off);
            r_s[i][lane] = x - fast_log2(s);
        }
        __syncthreads();
        // axis=1 (cols): y -= log2(sum_i 2^y)
#pragma unroll
        for (int jj = 0; jj < 4; ++jj) {
            int jc = w * 4 + jj;
            float x = r_s[lane][jc];
            float s = fast_exp2(x);
#pragma unroll
            for (int off = 32; off > 0; off >>= 1) s += __shfl_xor(s, off);
            r_s[lane][jc] = x - fast_log2(s);
        }
        __syncthreads();
    }

    // out = exp(r) = 2^y
    float* __restrict__ o = out + bh * 4096;
#pragma unroll
    for (int ii = 0; ii < 4; ++ii) {
        int i = w * 4 + ii;
        o[i * 64 + lane] = fast_exp2(r_s[i][lane]);
    }
}

extern "C" void kernel_launch(void* const* d_in, const int* in_sizes, int n_in,
                              void* d_out, int out_size, void* d_ws, size_t ws_size,
                              hipStream_t stream) {
    const float* q   = (const float*)d_in[0];
    const float* k   = (const float*)d_in[1];
    const float* qpe = (const float*)d_in[2];
    const float* kpe = (const float*)d_in[3];
    const float* gum = (const float*)d_in[4];
    float* out = (float*)d_out;

    float* sq = (float*)d_ws;                 // 32*64*64 floats = 512 KB
    float* sk = sq + BH * BUCKETS * DIM;      // another 512 KB

    bucket_mean_kernel<<<1024, 256, 0, stream>>>(q, k, qpe, kpe, sq, sk);
    sinkhorn_kernel<<<BH, 1024, 0, stream>>>(sq, sk, gum, out);
}